// Round 13
// baseline (679.667 us; speedup 1.0000x reference)
//
#include <hip/hip_runtime.h>

#define TT 96
#define FF 32
#define HH 128
#define G4 512
#define LOG2E 1.4426950408889634f

typedef _Float16 h2 __attribute__((ext_vector_type(2)));

__device__ __forceinline__ float fexp2(float x){ return __builtin_amdgcn_exp2f(x); }
__device__ __forceinline__ float frcp(float x){ return __builtin_amdgcn_rcpf(x); }
__device__ __forceinline__ float fsigmoid(float x){ return frcp(1.0f + fexp2(-LOG2E*x)); }
__device__ __forceinline__ float ftanh(float x){
    float u = fexp2(2.0f*LOG2E*x);
    return 1.0f - 2.0f*frcp(1.0f + u);
}
__device__ __forceinline__ h2 pk(float a, float b){
    h2 r; r.x = (_Float16)a; r.y = (_Float16)b; return r;
}
__device__ __forceinline__ unsigned pku(float a, float b){
    return __builtin_bit_cast(unsigned, pk(a, b));
}
__device__ __forceinline__ h2 u2h(unsigned v){ return __builtin_bit_cast(h2, v); }
__device__ __forceinline__ float fdot2(h2 a, h2 b, float c){
#if __has_builtin(__builtin_amdgcn_fdot2)
    return __builtin_amdgcn_fdot2(a, b, c, false);
#else
    return c + (float)a.x*(float)b.x + (float)a.y*(float)b.y;
#endif
}

// ---------------------------------------------------------------------------
// k_enc (round-27): r12 build + P2e/P3e fused into ONE phase (barriers 6->5):
// partials re-mapped so the jg-reduction is intra-wave (5 shfl_xor levels);
// exp + unnormalized x_tilde pack + per-wave softmax-sum in the same phase;
// P4e computes ss from 16 wave-sums and applies rs to the K-dot only.
// Prep stays merged as blocks 64..81.
// ---------------------------------------------------------------------------
__global__ __launch_bounds__(1024, 1)
void k_enc(const float* __restrict__ inputs,
           const float* __restrict__ enc_k,
           const float* __restrict__ enc_r,
           const float* __restrict__ enc_b,
           const float* __restrict__ ae_w1,
           const float* __restrict__ ae_b1,
           const float* __restrict__ ae_w2,
           const float* __restrict__ ad_w1,
           const float* __restrict__ fc_w,
           const float* __restrict__ fc_b,
           const float* __restrict__ dec_k,
           const float* __restrict__ dec_b,
           h2* __restrict__ Gp,
           float* __restrict__ gy,
           float* __restrict__ gb,
           float* __restrict__ ws_xenc,
           float* __restrict__ ws_xept){
    // ---- prep blocks (64..81): G/gy/gb for k_dec; independent of enc ----
    if (blockIdx.x >= 64){
        int blk = blockIdx.x - 64, tid = threadIdx.x;
        if (tid >= 256) return;
        int u0 = tid, u1 = tid + 256;
        if (blk < 16){
            float a0[8], a1[8];
            #pragma unroll
            for (int r = 0; r < 8; ++r){ a0[r] = 0.f; a1[r] = 0.f; }
            for (int m = 0; m < 128; ++m){
                float d0 = dec_k[m*G4 + u0], d1 = dec_k[m*G4 + u1];
                #pragma unroll
                for (int r = 0; r < 8; ++r){
                    float w = fc_w[(blk*8 + r)*HH + m];
                    a0[r] += w * d0; a1[r] += w * d1;
                }
            }
            #pragma unroll
            for (int c = 0; c < 4; ++c){
                Gp[(blk*G4 + u0)*4 + c] = pk(a0[2*c], a0[2*c+1]);
                Gp[(blk*G4 + u1)*4 + c] = pk(a1[2*c], a1[2*c+1]);
            }
        } else if (blk == 16){
            float a0 = 0.f, a1 = 0.f;
            for (int m = 0; m < 128; ++m){
                float w = fc_w[128*HH + m];
                a0 += w * dec_k[m*G4 + u0]; a1 += w * dec_k[m*G4 + u1];
            }
            gy[u0] = a0; gy[u1] = a1;
        } else {
            float a0 = 0.f, a1 = 0.f;
            for (int m = 0; m < 128; ++m){
                float w = fc_b[m];
                a0 += w * dec_k[m*G4 + u0]; a1 += w * dec_k[m*G4 + u1];
            }
            gb[u0] = a0 + dec_b[u0]; gb[u1] = a1 + dec_b[u1];
        }
        return;
    }

    extern __shared__ float lds[];
    uint4* KLH4 = (uint4*)lds;            // [4][512] uint4 = 8192 floats
    float* XPJT = lds + 8192;             // [128][33] = 4224
    float* XIN  = lds + 12416;            // [96][32]  = 3072
    float* HST  = lds + 15488;            // 256 (h, s fp32 state)
    float* PP   = lds + 15744;            // 1024 partials
    float* PPZ  = lds + 16768;            // 1024 z-halves
    float* PE   = lds + 17792;            // 128 (holds u = exp2(2L*PE))
    float* W2E  = lds + 17920;            // 128
    float* AB1E = lds + 18048;            // 128
    h2*    HSP  = (h2*)(lds + 18176);     // 128 h2
    h2*    XTP  = (h2*)(lds + 18240);     // 16 h2 (8 floats)
    _Float16* XEF = (_Float16*)(lds + 18248); // [96][128] f16 = 6144 floats
    float* WSUME= lds + 24392;            // 16 wave softmax-sums
    // total 24408 floats = 97632 B

    const int b = blockIdx.x, tid = threadIdx.x;
    const int u = tid & 511, hf = tid >> 9;
    const int j7 = tid & 127, g8 = tid >> 7;
    const float* xin_g = inputs + b*TT*FF;

    for (int i = tid; i < TT*FF; i += 1024) XIN[i] = xin_g[i];
    for (int i = tid; i < 2048; i += 1024){
        int f8 = i >> 9, uu = i & 511;
        uint4 q;
        q.x = pku(enc_k[(f8*8+0)*G4+uu], enc_k[(f8*8+1)*G4+uu]);
        q.y = pku(enc_k[(f8*8+2)*G4+uu], enc_k[(f8*8+3)*G4+uu]);
        q.z = pku(enc_k[(f8*8+4)*G4+uu], enc_k[(f8*8+5)*G4+uu]);
        q.w = pku(enc_k[(f8*8+6)*G4+uu], enc_k[(f8*8+7)*G4+uu]);
        KLH4[i] = q;
    }
    if (tid < 128){ W2E[tid] = ae_w2[tid]; AB1E[tid] = ae_b1[tid]; HSP[tid] = pk(0.f, 0.f); }
    if (tid < 256) HST[tid] = 0.f;

    // ---- step-invariant register caches ----
    h2 rp_e[32];
    #pragma unroll
    for (int i = 0; i < 32; ++i)
        rp_e[i] = pk(enc_r[(hf*64 + 2*i)*G4 + u], enc_r[(hf*64 + 2*i+1)*G4 + u]);

    uint4 wae[4];                             // ae_w1 rows 8m..8m+7, col j7 (coalesced)
    #pragma unroll
    for (int i4 = 0; i4 < 4; ++i4){
        int r0 = (g8*4 + i4)*8;
        wae[i4].x = pku(ae_w1[(r0+0)*HH + j7], ae_w1[(r0+1)*HH + j7]);
        wae[i4].y = pku(ae_w1[(r0+2)*HH + j7], ae_w1[(r0+3)*HH + j7]);
        wae[i4].z = pku(ae_w1[(r0+4)*HH + j7], ae_w1[(r0+5)*HH + j7]);
        wae[i4].w = pku(ae_w1[(r0+6)*HH + j7], ae_w1[(r0+7)*HH + j7]);
    }

    const float eb = (hf == 0) ? enc_b[u] : 0.f;
    __syncthreads();

    {   // XPJT[j][f] = sum_t x[t][f]*ae_w1[(256+t)*128+j]
        int j = tid & 127, fh = tid >> 7;
        float a0=0.f, a1=0.f, a2=0.f, a3=0.f;
        for (int t = 0; t < TT; ++t){
            float w = ae_w1[(256 + t)*HH + j];
            const float* xr = &XIN[t*FF + fh*4];
            a0 += xr[0]*w; a1 += xr[1]*w; a2 += xr[2]*w; a3 += xr[3]*w;
        }
        XPJT[j*33 + fh*4 + 0] = a0;
        XPJT[j*33 + fh*4 + 1] = a1;
        XPJT[j*33 + fh*4 + 2] = a2;
        XPJT[j*33 + fh*4 + 3] = a3;
    }
    __syncthreads();

    // fused-softmax role: wave wv6e covers f-pair {2w, 2w+1}; jg intra-wave
    const int l6e = tid & 63, wv6e = tid >> 6;
    const int fq = wv6e*2 + (l6e & 1), jgq = l6e >> 1;
    float er_e[4], sumw2e = 0.f;
    #pragma unroll
    for (int i = 0; i < 4; ++i){
        er_e[i] = fexp2(2.0f*LOG2E * XPJT[(jgq*4 + i)*33 + fq]);
        sumw2e += W2E[jgq*4 + i];
    }

    const uint4* HSP4 = (const uint4*)HSP;
    const uint4* XTP4 = (const uint4*)XTP;

    for (int t = 0; t < TT; ++t){
        float z = eb;
        // PH-A: att-proj partials — weights in REGISTERS, h broadcast
        {
            float a0 = 0.f, a1 = 0.f;
            #pragma unroll
            for (int i4 = 0; i4 < 4; ++i4){
                uint4 q  = HSP4[g8*4 + i4];     // broadcast
                uint4 wv = wae[i4];             // register
                a0 = fdot2(u2h(q.x), u2h(wv.x), a0);
                a1 = fdot2(u2h(q.y), u2h(wv.y), a1);
                a0 = fdot2(u2h(q.z), u2h(wv.z), a0);
                a1 = fdot2(u2h(q.w), u2h(wv.w), a1);
            }
            PP[tid] = a0 + a1;
        }
        // z-dot for waves 0-1 in P1 (they reduce in the next window)
        if (tid < 128){
            float z2 = 0.f;
            #pragma unroll
            for (int i4 = 0; i4 < 8; ++i4){
                uint4 q = HSP4[hf*8 + i4];
                z  = fdot2(u2h(q.x), rp_e[i4*4+0], z);
                z2 = fdot2(u2h(q.y), rp_e[i4*4+1], z2);
                z  = fdot2(u2h(q.z), rp_e[i4*4+2], z);
                z2 = fdot2(u2h(q.w), rp_e[i4*4+3], z2);
            }
            z += z2;
        }
        __syncthreads();  // B1
        // PE-reduce window: waves 0-1 reduce; waves 2-15 do their z-dot
        if (tid < 128){
            float s = AB1E[tid];
            #pragma unroll
            for (int g = 0; g < 8; ++g) s += PP[tid + 128*g];
            PE[tid] = fexp2(2.0f*LOG2E * s);   // store u, not s
        } else {
            float z2 = 0.f;
            #pragma unroll
            for (int i4 = 0; i4 < 8; ++i4){
                uint4 q = HSP4[hf*8 + i4];
                z  = fdot2(u2h(q.x), rp_e[i4*4+0], z);
                z2 = fdot2(u2h(q.y), rp_e[i4*4+1], z2);
                z  = fdot2(u2h(q.z), rp_e[i4*4+2], z);
                z2 = fdot2(u2h(q.w), rp_e[i4*4+3], z2);
            }
            z += z2;
        }
        __syncthreads();  // B2
        {   // P2e' (fused P2e+P3e): tanh partial + intra-wave jg-reduce +
            // exp + UNNORMALIZED x_tilde pack + per-wave softmax-sum
            float acc2 = 0.f;
            #pragma unroll
            for (int i = 0; i < 4; ++i){
                float uu = PE[jgq*4 + i];
                float wq = W2E[jgq*4 + i];
                acc2 += wq * frcp(fmaf(er_e[i], uu, 1.0f));
            }
            float part = sumw2e - 2.0f*acc2;
            part += __shfl_xor(part, 2);
            part += __shfl_xor(part, 4);
            part += __shfl_xor(part, 8);
            part += __shfl_xor(part, 16);
            part += __shfl_xor(part, 32);
            float p = fexp2(part * LOG2E);
            float xt = p * XIN[t*FF + fq];
            float xt2 = __shfl_xor(xt, 1);
            float pss = (jgq == 0) ? p : 0.f;
            pss += __shfl_xor(pss, 1);
            if (l6e == 0){
                XTP[wv6e] = pk(xt, xt2);
                WSUME[wv6e] = pss;
            }
        }
        __syncthreads();  // B3
        {   // P4e: ss from wave-sums; z += (x_tilde @ enc_k) * rs
            float ssn = 0.f;
            #pragma unroll
            for (int g = 0; g < 16; ++g) ssn += WSUME[g];
            float rs = frcp(ssn);
            float zk = 0.f, zk2 = 0.f;
            #pragma unroll
            for (int c = 0; c < 2; ++c){
                int f8 = hf*2 + c;
                uint4 kq = KLH4[f8*512 + u];
                uint4 xq = XTP4[f8];
                zk  = fdot2(u2h(kq.x), u2h(xq.x), zk);
                zk2 = fdot2(u2h(kq.y), u2h(xq.y), zk2);
                zk  = fdot2(u2h(kq.z), u2h(xq.z), zk);
                zk2 = fdot2(u2h(kq.w), u2h(xq.w), zk2);
            }
            z += (zk + zk2) * rs;
            PPZ[hf*512 + u] = z;
        }
        __syncthreads();  // B4
        if (tid < 128){
            int j = tid;
            float zi = PPZ[j]       + PPZ[512 + j];
            float zf = PPZ[128 + j] + PPZ[640 + j];
            float zg = PPZ[256 + j] + PPZ[768 + j];
            float zo = PPZ[384 + j] + PPZ[896 + j];
            float iv = fsigmoid(zi);
            float fv = fsigmoid(zf);
            float gv = ftanh(zg);
            float ov = fsigmoid(zo);
            float cn = fv * HST[128 + j] + iv * gv;
            float hn = ov * ftanh(cn);
            HST[128 + j] = cn;
            HST[j] = hn;
            ws_xenc[(b*TT + t)*HH + j] = hn;
            XEF[t*HH + j] = (_Float16)hn;      // f16 copy for xept tail
            float hn2 = __shfl_xor(hn, 1);
            float cn2 = __shfl_xor(cn, 1);
            if (!(j & 1)){
                HSP[j >> 1]        = pk(hn, hn2);
                HSP[64 + (j >> 1)] = pk(cn, cn2);
            }
        }
        __syncthreads();  // B5
    }

    // xept tail: ws_xept[(b*HH+j)*TT+tp] = sum_k xe[tp][k]*ad_w1[(256+k)*HH+j]
    {
        int j = tid & 127, th = tid >> 7;     // th: 8 groups x 12 t'
        float acc[12];
        #pragma unroll
        for (int i = 0; i < 12; ++i) acc[i] = 0.f;
        for (int k = 0; k < 128; ++k){
            float w = ad_w1[(256 + k)*HH + j];
            #pragma unroll
            for (int i = 0; i < 12; ++i)
                acc[i] += (float)XEF[(th*12 + i)*HH + k] * w;   // wave-uniform -> broadcast
        }
        #pragma unroll
        for (int i = 0; i < 12; ++i)
            ws_xept[(b*HH + j)*TT + th*12 + i] = acc[i];
    }
}

// ---------------------------------------------------------------------------
// k_dec (round-27): r10 build + P2/P3 fused into ONE phase (barriers 7->6):
// e-partials re-mapped so the 8 og-partials of each t' live in one wave
// (lane = tpl*8+og; 16 waves x 6 tp = 96); 3 shfl_xor levels replace the
// LDS round-trip; exp + BEP pack + per-wave sum in the same phase; P4
// computes ss from WSUM and folds 1/ss into the ctx scale.
// ---------------------------------------------------------------------------
__global__ __launch_bounds__(1024, 1)
void k_dec(const float* __restrict__ inputs,
           const float* __restrict__ dec_r,
           const float* __restrict__ ad_w1,
           const float* __restrict__ ad_b1,
           const float* __restrict__ ad_w2,
           const float* __restrict__ ff_w,
           const float* __restrict__ ff_b,
           const h2* __restrict__ Gp,
           const float* __restrict__ gy,
           const float* __restrict__ gb,
           const float* __restrict__ ws_xenc,
           const float* __restrict__ ws_xept,
           float* __restrict__ out){
    extern __shared__ float lds[];
    uint4* XE4 = (uint4*)lds;             // [12][128] uint4 = 6144 floats
    uint4* WDC4= (uint4*)(lds + 6144);    // [32][128] uint4 = 16384 floats
    float* PP  = lds + 22528;             // 1024 (unused in loop now; epilogue)
    float* PPZ = lds + 23552;             // 1024
    float* PPA = lds + 24576;             // 1024 (APJ eighth-partials)
    float* APJ = lds + 25600;             // 128 (holds u = exp2(2L*APJ))
    float* DST = lds + 25728;             // 256: d, c
    float* CTX = lds + 25984;             // 128
    float* WSUM= lds + 26112;             // 16 wave softmax-sums (old W2L slot)
    float* YV  = lds + 26240;             // 96
    float* SCAL= lds + 26336;             // 8 (unused)
    h2*    DCP = (h2*)(lds + 26344);      // 128 h2 (d pairs 0..63, c pairs 64..127)
    h2*    CXP = (h2*)(lds + 26408);      // 64 h2
    h2*    BEP = (h2*)(lds + 26440);      // 64 h2 (48 used)
    // total 26472 floats = 105888 B

    const int b = blockIdx.x, tid = threadIdx.x;
    const int u = tid & 511, hf = tid >> 9;    // z-half role
    const int j = tid & 127, og = tid >> 7;    // APJ-eighth role

    {   // x_enc -> LDS f16 t-pairs
        const float* xe_g = ws_xenc + b*TT*HH;
        for (int i = tid; i < 12*HH; i += 1024){
            int t8 = i >> 7, k = i & 127;
            uint4 qq;
            qq.x = pku(xe_g[(t8*8 + 0)*HH + k], xe_g[(t8*8 + 1)*HH + k]);
            qq.y = pku(xe_g[(t8*8 + 2)*HH + k], xe_g[(t8*8 + 3)*HH + k]);
            qq.z = pku(xe_g[(t8*8 + 4)*HH + k], xe_g[(t8*8 + 5)*HH + k]);
            qq.w = pku(xe_g[(t8*8 + 6)*HH + k], xe_g[(t8*8 + 7)*HH + k]);
            XE4[i] = qq;
        }
    }
    // ad_w1 rows 0..255 -> f16 LDS
    for (int i = tid; i < 4096; i += 1024){
        int jj = i & 127, i4g = i >> 7;
        int kbase = (i4g >> 2)*32 + (i4g & 3)*8;
        uint4 wv;
        wv.x = pku(ad_w1[(kbase+0)*HH + jj], ad_w1[(kbase+1)*HH + jj]);
        wv.y = pku(ad_w1[(kbase+2)*HH + jj], ad_w1[(kbase+3)*HH + jj]);
        wv.z = pku(ad_w1[(kbase+4)*HH + jj], ad_w1[(kbase+5)*HH + jj]);
        wv.w = pku(ad_w1[(kbase+6)*HH + jj], ad_w1[(kbase+7)*HH + jj]);
        WDC4[i] = wv;
    }
    if (tid < TT) YV[tid] = inputs[b*TT*FF + tid*FF + (FF-1)];
    if (tid < 128) DCP[tid] = pk(0.f, 0.f);
    if (tid < 256) DST[tid] = 0.f;

    // ---- step-invariant register caches ----
    h2 rp[32];                                  // dec_r half-column
    #pragma unroll
    for (int i = 0; i < 32; ++i)
        rp[i] = pk(dec_r[(hf*64 + 2*i)*G4 + u], dec_r[(hf*64 + 2*i+1)*G4 + u]);

    uint4 Greg[8];                              // G half-column (ctx weights)
    {
        const uint4* GQ = (const uint4*)Gp;
        #pragma unroll
        for (int g = 0; g < 8; ++g) Greg[g] = GQ[(hf*8 + g)*G4 + u];
    }

    // fused-softmax role: wave wv6 covers tp = wv6*6 + tpl (tpl<6), ogn intra-wave
    const int l6 = tid & 63, wv6 = tid >> 6;
    const int ogn = l6 & 7, tpl = l6 >> 3;
    const int tpn = wv6*6 + tpl;
    const bool act = (tpl < 6);
    // w2-folded factorization: w2*rcp(1+er*u) == rcp(iw + erw*u)
    float erw[16], iw[16], sumw2 = 0.f;
    {
        const float* xp_g = ws_xept + (b*HH + ogn*16)*TT + tpn;
        #pragma unroll
        for (int i = 0; i < 16; ++i){
            float w2v = ad_w2[ogn*16 + i];
            float ivv = 1.0f / w2v;
            iw[i] = ivv;
            sumw2 += w2v;
            float xp = act ? xp_g[i*TT] : 0.f;
            erw[i] = fexp2(2.0f*LOG2E * xp) * ivv;
        }
    }

    const float gbr = gb[u], gyr = gy[u];
    const float ab1 = (tid < 128) ? ad_b1[tid] : 0.f;
    __syncthreads();

    const uint4* DCP4 = (const uint4*)DCP;
    const uint4* CXP4 = (const uint4*)CXP;
    const uint4* BEP4 = (const uint4*)BEP;

    for (int t = 0; t < TT; ++t){
        float z = (hf == 0) ? (gbr + YV[t]*gyr) : 0.f;
        // P1: APJ eighth-partial (ALL threads)
        {
            float s0 = 0.f, s1 = 0.f;
            #pragma unroll
            for (int i = 0; i < 4; ++i){
                uint4 dq = DCP4[og*4 + i];              // wave-uniform broadcast
                uint4 wv = WDC4[(og*4 + i)*128 + j];    // lane-consecutive
                s0 = fdot2(u2h(dq.x), u2h(wv.x), s0);
                s1 = fdot2(u2h(dq.y), u2h(wv.y), s1);
                s0 = fdot2(u2h(dq.z), u2h(wv.z), s0);
                s1 = fdot2(u2h(dq.w), u2h(wv.w), s1);
            }
            PPA[og*128 + j] = s0 + s1;
        }
        // z-dot for waves 0-1 here (they reduce in the next window)
        if (tid < 128){
            float z2 = 0.f;
            #pragma unroll
            for (int i4 = 0; i4 < 8; ++i4){
                uint4 q = DCP4[hf*8 + i4];
                z  = fdot2(u2h(q.x), rp[i4*4+0], z);
                z2 = fdot2(u2h(q.y), rp[i4*4+1], z2);
                z  = fdot2(u2h(q.z), rp[i4*4+2], z);
                z2 = fdot2(u2h(q.w), rp[i4*4+3], z2);
            }
            z += z2;
        }
        __syncthreads();  // B1
        // P1b window: waves 0-1 reduce APJ; waves 2-15 do their z-dot
        if (tid < 128){
            float s = ab1;
            #pragma unroll
            for (int g = 0; g < 8; ++g) s += PPA[tid + 128*g];
            APJ[tid] = fexp2(2.0f*LOG2E * s);
        } else {
            float z2 = 0.f;
            #pragma unroll
            for (int i4 = 0; i4 < 8; ++i4){
                uint4 q = DCP4[hf*8 + i4];
                z  = fdot2(u2h(q.x), rp[i4*4+0], z);
                z2 = fdot2(u2h(q.y), rp[i4*4+1], z2);
                z  = fdot2(u2h(q.z), rp[i4*4+2], z);
                z2 = fdot2(u2h(q.w), rp[i4*4+3], z2);
            }
            z += z2;
        }
        __syncthreads();  // B1b
        // P2' (fused P2+P3): e-partials + intra-wave og-reduce + exp +
        // BEP pack + per-wave softmax-sum
        {
            float part = 0.f;
            if (act){
                float acc2 = 0.f;
                #pragma unroll
                for (int q4 = 0; q4 < 4; ++q4){
                    float4 uj = *(const float4*)&APJ[ogn*16 + q4*4];
                    acc2 += frcp(fmaf(erw[q4*4+0], uj.x, iw[q4*4+0]));
                    acc2 += frcp(fmaf(erw[q4*4+1], uj.y, iw[q4*4+1]));
                    acc2 += frcp(fmaf(erw[q4*4+2], uj.z, iw[q4*4+2]));
                    acc2 += frcp(fmaf(erw[q4*4+3], uj.w, iw[q4*4+3]));
                }
                part = sumw2 - 2.0f*acc2;
            }
            part += __shfl_xor(part, 1);
            part += __shfl_xor(part, 2);
            part += __shfl_xor(part, 4);
            float p = fexp2(part * LOG2E);
            float p2 = __shfl_xor(p, 8);
            if (act && ogn == 0 && !(tpl & 1))
                BEP[wv6*3 + (tpl >> 1)] = pk(p, p2);
            float pss = (act && ogn == 0) ? p : 0.f;
            pss += __shfl_xor(pss, 8);
            pss += __shfl_xor(pss, 16);
            pss += __shfl_xor(pss, 32);
            if (l6 == 0) WSUM[wv6] = pss;
        }
        __syncthreads();  // B2
        // P4: FULL ctx[k] (tid<128); ss from wave-sums, rs folded into scale
        if (tid < 128){
            float ssn = 0.f;
            #pragma unroll
            for (int g = 0; g < 16; ++g) ssn += WSUM[g];
            float rs = frcp(ssn);
            float s0 = 0.f, s1 = 0.f;
            #pragma unroll
            for (int t8 = 0; t8 < 12; t8 += 2){
                uint4 xq0 = XE4[t8*HH + tid],     bb0 = BEP4[t8];
                uint4 xq1 = XE4[(t8+1)*HH + tid], bb1 = BEP4[t8+1];
                s0 = fdot2(u2h(xq0.x), u2h(bb0.x), s0);
                s1 = fdot2(u2h(xq0.y), u2h(bb0.y), s1);
                s0 = fdot2(u2h(xq0.z), u2h(bb0.z), s0);
                s1 = fdot2(u2h(xq0.w), u2h(bb0.w), s1);
                s0 = fdot2(u2h(xq1.x), u2h(bb1.x), s0);
                s1 = fdot2(u2h(xq1.y), u2h(bb1.y), s1);
                s0 = fdot2(u2h(xq1.z), u2h(bb1.z), s0);
                s1 = fdot2(u2h(xq1.w), u2h(bb1.w), s1);
            }
            float cv = (s0 + s1) * rs;
            CTX[tid] = cv;
            float cv2 = __shfl_xor(cv, 1);
            if (!(tid & 1)) CXP[tid >> 1] = pk(cv, cv2);
        }
        __syncthreads();  // B4
        // P5: z-half += ctx @ G (G in registers, ctx broadcast from LDS)
        {
            float z2 = 0.f;
            #pragma unroll
            for (int gi = 0; gi < 8; ++gi){
                uint4 q  = Greg[gi];
                uint4 cc = CXP4[hf*8 + gi];
                z  = fdot2(u2h(q.x), u2h(cc.x), z);
                z2 = fdot2(u2h(q.y), u2h(cc.y), z2);
                z  = fdot2(u2h(q.z), u2h(cc.z), z);
                z2 = fdot2(u2h(q.w), u2h(cc.w), z2);
            }
            PPZ[hf*512 + u] = z + z2;
        }
        __syncthreads();  // B5
        // P6: gates (combine z-halves) + packed-state update
        if (tid < 128){
            int jj = tid;
            float zi = PPZ[jj]       + PPZ[512 + jj];
            float zf = PPZ[128 + jj] + PPZ[640 + jj];
            float zg = PPZ[256 + jj] + PPZ[768 + jj];
            float zo = PPZ[384 + jj] + PPZ[896 + jj];
            float iv = fsigmoid(zi);
            float fv = fsigmoid(zf);
            float gv = ftanh(zg);
            float ov = fsigmoid(zo);
            float cn = fv * DST[128 + jj] + iv * gv;
            float hn = ov * ftanh(cn);
            DST[128 + jj] = cn;
            DST[jj] = hn;
            float hn2 = __shfl_xor(hn, 1);
            float cn2 = __shfl_xor(cn, 1);
            if (!(jj & 1)){
                DCP[jj >> 1]        = pk(hn, hn2);
                DCP[64 + (jj >> 1)] = pk(cn, cn2);
            }
        }
        __syncthreads();  // B6
    }

    // output: y_pred = [d_n, ctx] @ ff_w + ff_b (fp32)
    {
        int jp = tid & 31, sg = tid >> 5;
        float a = 0.f;
        #pragma unroll
        for (int kk = 0; kk < 8; ++kk){
            int k = sg*8 + kk;
            float val = (k < 128) ? DST[k] : CTX[k - 128];
            a += val * ff_w[k*FF + jp];
        }
        PP[sg*32 + jp] = a;
    }
    __syncthreads();
    if (tid < 32){
        float o = ff_b[tid];
        #pragma unroll
        for (int s = 0; s < 32; ++s) o += PP[s*32 + tid];
        out[b*FF + tid] = o;
    }
}

// ---------------------------------------------------------------------------
extern "C" void kernel_launch(void* const* d_in, const int* in_sizes, int n_in,
                              void* d_out, int out_size, void* d_ws, size_t ws_size,
                              hipStream_t stream) {
    const float* inputs = (const float*)d_in[0];
    const float* enc_k  = (const float*)d_in[1];
    const float* enc_r  = (const float*)d_in[2];
    const float* enc_b  = (const float*)d_in[3];
    const float* ae_w1  = (const float*)d_in[4];
    const float* ae_b1  = (const float*)d_in[5];
    const float* ae_w2  = (const float*)d_in[6];
    // d_in[7] = ae_b2 (softmax-invariant, unused)
    const float* dec_k  = (const float*)d_in[8];
    const float* dec_r  = (const float*)d_in[9];
    const float* dec_b  = (const float*)d_in[10];
    const float* ad_w1  = (const float*)d_in[11];
    const float* ad_b1  = (const float*)d_in[12];
    const float* ad_w2  = (const float*)d_in[13];
    // d_in[14] = ad_b2 (softmax-invariant, unused)
    const float* fc_w   = (const float*)d_in[15];
    const float* fc_b   = (const float*)d_in[16];
    const float* ff_w   = (const float*)d_in[17];
    const float* ff_b   = (const float*)d_in[18];

    float* ws      = (float*)d_ws;
    float* ws_xenc = ws;                     // 64*96*128 floats
    float* ws_xept = ws + 786432;            // 64*128*96 floats
    h2*    Gp      = (h2*)(ws + 1572864);    // 32768 h2 (128 KB)
    float* gy      = ws + 1605632;           // 512
    float* gb      = ws + 1606144;           // 512

    hipFuncSetAttribute((const void*)k_enc, hipFuncAttributeMaxDynamicSharedMemorySize, 97632);
    hipFuncSetAttribute((const void*)k_dec, hipFuncAttributeMaxDynamicSharedMemorySize, 105888);

    // prep is merged into k_enc as blocks 64..81 (runs on idle CUs)
    k_enc<<<82, 1024, 97632, stream>>>(inputs, enc_k, enc_r, enc_b, ae_w1, ae_b1, ae_w2,
                                       ad_w1, fc_w, fc_b, dec_k, dec_b, Gp, gy, gb,
                                       ws_xenc, ws_xept);
    k_dec<<<64, 1024, 105888, stream>>>(inputs, dec_r, ad_w1, ad_b1, ad_w2, ff_w, ff_b,
                                        Gp, gy, gb, ws_xenc, ws_xept, (float*)d_out);
}

// Round 14
// 650.978 us; speedup vs baseline: 1.0441x; 1.0441x over previous
//
#include <hip/hip_runtime.h>

#define TT 96
#define FF 32
#define HH 128
#define G4 512
#define LOG2E 1.4426950408889634f

typedef _Float16 h2 __attribute__((ext_vector_type(2)));

__device__ __forceinline__ float fexp2(float x){ return __builtin_amdgcn_exp2f(x); }
__device__ __forceinline__ float frcp(float x){ return __builtin_amdgcn_rcpf(x); }
__device__ __forceinline__ float fsigmoid(float x){ return frcp(1.0f + fexp2(-LOG2E*x)); }
__device__ __forceinline__ float ftanh(float x){
    float u = fexp2(2.0f*LOG2E*x);
    return 1.0f - 2.0f*frcp(1.0f + u);
}
__device__ __forceinline__ h2 pk(float a, float b){
    h2 r; r.x = (_Float16)a; r.y = (_Float16)b; return r;
}
__device__ __forceinline__ unsigned pku(float a, float b){
    return __builtin_bit_cast(unsigned, pk(a, b));
}
__device__ __forceinline__ h2 u2h(unsigned v){ return __builtin_bit_cast(h2, v); }
__device__ __forceinline__ float fdot2(h2 a, h2 b, float c){
#if __has_builtin(__builtin_amdgcn_fdot2)
    return __builtin_amdgcn_fdot2(a, b, c, false);
#else
    return c + (float)a.x*(float)b.x + (float)a.y*(float)b.y;
#endif
}

// ---------------------------------------------------------------------------
// k_enc: exact round-12/660µs build (wae-hoist + window motion + P3e spread +
// prep merged as blocks 64..81). The r13 enc fusion regressed — reverted.
// ---------------------------------------------------------------------------
__global__ __launch_bounds__(1024, 1)
void k_enc(const float* __restrict__ inputs,
           const float* __restrict__ enc_k,
           const float* __restrict__ enc_r,
           const float* __restrict__ enc_b,
           const float* __restrict__ ae_w1,
           const float* __restrict__ ae_b1,
           const float* __restrict__ ae_w2,
           const float* __restrict__ ad_w1,
           const float* __restrict__ fc_w,
           const float* __restrict__ fc_b,
           const float* __restrict__ dec_k,
           const float* __restrict__ dec_b,
           h2* __restrict__ Gp,
           float* __restrict__ gy,
           float* __restrict__ gb,
           float* __restrict__ ws_xenc,
           float* __restrict__ ws_xept){
    // ---- prep blocks (64..81): G/gy/gb for k_dec; independent of enc ----
    if (blockIdx.x >= 64){
        int blk = blockIdx.x - 64, tid = threadIdx.x;
        if (tid >= 256) return;
        int u0 = tid, u1 = tid + 256;
        if (blk < 16){
            float a0[8], a1[8];
            #pragma unroll
            for (int r = 0; r < 8; ++r){ a0[r] = 0.f; a1[r] = 0.f; }
            for (int m = 0; m < 128; ++m){
                float d0 = dec_k[m*G4 + u0], d1 = dec_k[m*G4 + u1];
                #pragma unroll
                for (int r = 0; r < 8; ++r){
                    float w = fc_w[(blk*8 + r)*HH + m];
                    a0[r] += w * d0; a1[r] += w * d1;
                }
            }
            #pragma unroll
            for (int c = 0; c < 4; ++c){
                Gp[(blk*G4 + u0)*4 + c] = pk(a0[2*c], a0[2*c+1]);
                Gp[(blk*G4 + u1)*4 + c] = pk(a1[2*c], a1[2*c+1]);
            }
        } else if (blk == 16){
            float a0 = 0.f, a1 = 0.f;
            for (int m = 0; m < 128; ++m){
                float w = fc_w[128*HH + m];
                a0 += w * dec_k[m*G4 + u0]; a1 += w * dec_k[m*G4 + u1];
            }
            gy[u0] = a0; gy[u1] = a1;
        } else {
            float a0 = 0.f, a1 = 0.f;
            for (int m = 0; m < 128; ++m){
                float w = fc_b[m];
                a0 += w * dec_k[m*G4 + u0]; a1 += w * dec_k[m*G4 + u1];
            }
            gb[u0] = a0 + dec_b[u0]; gb[u1] = a1 + dec_b[u1];
        }
        return;
    }

    extern __shared__ float lds[];
    uint4* KLH4 = (uint4*)lds;            // [4][512] uint4 = 8192 floats
    float* XPJT = lds + 8192;             // [128][33] = 4224
    float* XIN  = lds + 12416;            // [96][32]  = 3072
    float* HST  = lds + 15488;            // 256 (h, s fp32 state)
    float* PP   = lds + 15744;            // 1024 partials
    float* PPZ  = lds + 16768;            // 1024 z-halves
    float* PE   = lds + 17792;            // 128 (holds u = exp2(2L*PE))
    float* W2E  = lds + 17920;            // 128
    float* AB1E = lds + 18048;            // 128
    h2*    HSP  = (h2*)(lds + 18176);     // 128 h2
    h2*    XTP  = (h2*)(lds + 18240);     // 16 h2 (8 floats)
    _Float16* XEF = (_Float16*)(lds + 18248); // [96][128] f16 = 6144 floats
    // total 24392 floats = 97568 B

    const int b = blockIdx.x, tid = threadIdx.x;
    const int u = tid & 511, hf = tid >> 9;
    const int j7 = tid & 127, g8 = tid >> 7;
    const float* xin_g = inputs + b*TT*FF;

    for (int i = tid; i < TT*FF; i += 1024) XIN[i] = xin_g[i];
    for (int i = tid; i < 2048; i += 1024){
        int f8 = i >> 9, uu = i & 511;
        uint4 q;
        q.x = pku(enc_k[(f8*8+0)*G4+uu], enc_k[(f8*8+1)*G4+uu]);
        q.y = pku(enc_k[(f8*8+2)*G4+uu], enc_k[(f8*8+3)*G4+uu]);
        q.z = pku(enc_k[(f8*8+4)*G4+uu], enc_k[(f8*8+5)*G4+uu]);
        q.w = pku(enc_k[(f8*8+6)*G4+uu], enc_k[(f8*8+7)*G4+uu]);
        KLH4[i] = q;
    }
    if (tid < 128){ W2E[tid] = ae_w2[tid]; AB1E[tid] = ae_b1[tid]; HSP[tid] = pk(0.f, 0.f); }
    if (tid < 256) HST[tid] = 0.f;

    // ---- step-invariant register caches ----
    h2 rp_e[32];
    #pragma unroll
    for (int i = 0; i < 32; ++i)
        rp_e[i] = pk(enc_r[(hf*64 + 2*i)*G4 + u], enc_r[(hf*64 + 2*i+1)*G4 + u]);

    uint4 wae[4];                             // ae_w1 rows 8m..8m+7, col j7 (coalesced)
    #pragma unroll
    for (int i4 = 0; i4 < 4; ++i4){
        int r0 = (g8*4 + i4)*8;
        wae[i4].x = pku(ae_w1[(r0+0)*HH + j7], ae_w1[(r0+1)*HH + j7]);
        wae[i4].y = pku(ae_w1[(r0+2)*HH + j7], ae_w1[(r0+3)*HH + j7]);
        wae[i4].z = pku(ae_w1[(r0+4)*HH + j7], ae_w1[(r0+5)*HH + j7]);
        wae[i4].w = pku(ae_w1[(r0+6)*HH + j7], ae_w1[(r0+7)*HH + j7]);
    }

    const float eb = (hf == 0) ? enc_b[u] : 0.f;
    __syncthreads();

    {   // XPJT[j][f] = sum_t x[t][f]*ae_w1[(256+t)*128+j]
        int j = tid & 127, fh = tid >> 7;
        float a0=0.f, a1=0.f, a2=0.f, a3=0.f;
        for (int t = 0; t < TT; ++t){
            float w = ae_w1[(256 + t)*HH + j];
            const float* xr = &XIN[t*FF + fh*4];
            a0 += xr[0]*w; a1 += xr[1]*w; a2 += xr[2]*w; a3 += xr[3]*w;
        }
        XPJT[j*33 + fh*4 + 0] = a0;
        XPJT[j*33 + fh*4 + 1] = a1;
        XPJT[j*33 + fh*4 + 2] = a2;
        XPJT[j*33 + fh*4 + 3] = a3;
    }
    __syncthreads();

    // tanh factorization (r8 form: er_e + W2E broadcast; fits reg budget)
    const int f5 = tid & 31, jg5 = tid >> 5;
    float er_e[4], sumw2e = 0.f;
    #pragma unroll
    for (int i = 0; i < 4; ++i){
        er_e[i] = fexp2(2.0f*LOG2E * XPJT[(jg5*4 + i)*33 + f5]);
        sumw2e += W2E[jg5*4 + i];
    }

    const uint4* HSP4 = (const uint4*)HSP;
    const uint4* XTP4 = (const uint4*)XTP;

    for (int t = 0; t < TT; ++t){
        float z = eb;
        // PH-A: att-proj partials — weights in REGISTERS, h broadcast
        {
            float a0 = 0.f, a1 = 0.f;
            #pragma unroll
            for (int i4 = 0; i4 < 4; ++i4){
                uint4 q  = HSP4[g8*4 + i4];     // broadcast
                uint4 wv = wae[i4];             // register
                a0 = fdot2(u2h(q.x), u2h(wv.x), a0);
                a1 = fdot2(u2h(q.y), u2h(wv.y), a1);
                a0 = fdot2(u2h(q.z), u2h(wv.z), a0);
                a1 = fdot2(u2h(q.w), u2h(wv.w), a1);
            }
            PP[tid] = a0 + a1;
        }
        // z-dot for waves 0-1 in P1 (they reduce in the next window)
        if (tid < 128){
            float z2 = 0.f;
            #pragma unroll
            for (int i4 = 0; i4 < 8; ++i4){
                uint4 q = HSP4[hf*8 + i4];
                z  = fdot2(u2h(q.x), rp_e[i4*4+0], z);
                z2 = fdot2(u2h(q.y), rp_e[i4*4+1], z2);
                z  = fdot2(u2h(q.z), rp_e[i4*4+2], z);
                z2 = fdot2(u2h(q.w), rp_e[i4*4+3], z2);
            }
            z += z2;
        }
        __syncthreads();  // B1
        // PE-reduce window: waves 0-1 reduce; waves 2-15 do their z-dot
        if (tid < 128){
            float s = AB1E[tid];
            #pragma unroll
            for (int g = 0; g < 8; ++g) s += PP[tid + 128*g];
            PE[tid] = fexp2(2.0f*LOG2E * s);   // store u, not s
        } else {
            float z2 = 0.f;
            #pragma unroll
            for (int i4 = 0; i4 < 8; ++i4){
                uint4 q = HSP4[hf*8 + i4];
                z  = fdot2(u2h(q.x), rp_e[i4*4+0], z);
                z2 = fdot2(u2h(q.y), rp_e[i4*4+1], z2);
                z  = fdot2(u2h(q.z), rp_e[i4*4+2], z);
                z2 = fdot2(u2h(q.w), rp_e[i4*4+3], z2);
            }
            z += z2;
        }
        __syncthreads();  // B2
        {   // P2e: factorized tanh — 1 rcp/element, broadcasts only
            float acc2 = 0.f;
            #pragma unroll
            for (int i = 0; i < 4; ++i){
                float uu = PE[jg5*4 + i];       // broadcast
                float w  = W2E[jg5*4 + i];      // broadcast
                acc2 += w * frcp(fmaf(er_e[i], uu, 1.0f));
            }
            PP[tid] = sumw2e - 2.0f*acc2;
        }
        __syncthreads();  // B3
        // P3e: column-sum over 64 lanes (16-deep chain), softmax, x_tilde
        if (tid < 64){
            int f = tid & 31, hh = tid >> 5;
            float e = 0.f;
            #pragma unroll
            for (int g = 0; g < 16; ++g) e += PP[(hh*16 + g)*32 + f];
            e += __shfl_xor(e, 32, 64);         // combine halves
            float p = fexp2(e * LOG2E);
            float ss = p;
            #pragma unroll
            for (int d = 16; d; d >>= 1) ss += __shfl_xor(ss, d, 32);
            if (tid < 32){
                float xt = p * frcp(ss) * XIN[t*FF + tid];
                float xt2 = __shfl_xor(xt, 1);
                if (!(tid & 1)) XTP[tid >> 1] = pk(xt, xt2);
            }
        }
        __syncthreads();  // B4
        {
            float z2 = 0.f;
            #pragma unroll
            for (int c = 0; c < 2; ++c){
                int f8 = hf*2 + c;
                uint4 kq = KLH4[f8*512 + u];
                uint4 xq = XTP4[f8];
                z  = fdot2(u2h(kq.x), u2h(xq.x), z);
                z2 = fdot2(u2h(kq.y), u2h(xq.y), z2);
                z  = fdot2(u2h(kq.z), u2h(xq.z), z);
                z2 = fdot2(u2h(kq.w), u2h(xq.w), z2);
            }
            PPZ[hf*512 + u] = z + z2;
        }
        __syncthreads();  // B5
        if (tid < 128){
            int j = tid;
            float zi = PPZ[j]       + PPZ[512 + j];
            float zf = PPZ[128 + j] + PPZ[640 + j];
            float zg = PPZ[256 + j] + PPZ[768 + j];
            float zo = PPZ[384 + j] + PPZ[896 + j];
            float iv = fsigmoid(zi);
            float fv = fsigmoid(zf);
            float gv = ftanh(zg);
            float ov = fsigmoid(zo);
            float cn = fv * HST[128 + j] + iv * gv;
            float hn = ov * ftanh(cn);
            HST[128 + j] = cn;
            HST[j] = hn;
            ws_xenc[(b*TT + t)*HH + j] = hn;
            XEF[t*HH + j] = (_Float16)hn;      // f16 copy for xept tail
            float hn2 = __shfl_xor(hn, 1);
            float cn2 = __shfl_xor(cn, 1);
            if (!(j & 1)){
                HSP[j >> 1]        = pk(hn, hn2);
                HSP[64 + (j >> 1)] = pk(cn, cn2);
            }
        }
        __syncthreads();  // B6
    }

    // xept tail: ws_xept[(b*HH+j)*TT+tp] = sum_k xe[tp][k]*ad_w1[(256+k)*HH+j]
    {
        int j = tid & 127, th = tid >> 7;     // th: 8 groups x 12 t'
        float acc[12];
        #pragma unroll
        for (int i = 0; i < 12; ++i) acc[i] = 0.f;
        for (int k = 0; k < 128; ++k){
            float w = ad_w1[(256 + k)*HH + j];
            #pragma unroll
            for (int i = 0; i < 12; ++i)
                acc[i] += (float)XEF[(th*12 + i)*HH + k] * w;   // wave-uniform -> broadcast
        }
        #pragma unroll
        for (int i = 0; i < 12; ++i)
            ws_xept[(b*HH + j)*TT + th*12 + i] = acc[i];
    }
}

// ---------------------------------------------------------------------------
// k_dec (round-28): r13's fused P2'+P3 build (359.5µs, verified) with the
// 4-way APJ bank conflict FIXED: padded APJ_P groups at stride 20 floats
// (bank bases ogn*20 mod 32 = {0,20,8,28,16,4,24,12} — all distinct,
// conflict-free, 16B-aligned for float4). Writer/reader index change only.
// ---------------------------------------------------------------------------
__global__ __launch_bounds__(1024, 1)
void k_dec(const float* __restrict__ inputs,
           const float* __restrict__ dec_r,
           const float* __restrict__ ad_w1,
           const float* __restrict__ ad_b1,
           const float* __restrict__ ad_w2,
           const float* __restrict__ ff_w,
           const float* __restrict__ ff_b,
           const h2* __restrict__ Gp,
           const float* __restrict__ gy,
           const float* __restrict__ gb,
           const float* __restrict__ ws_xenc,
           const float* __restrict__ ws_xept,
           float* __restrict__ out){
    extern __shared__ float lds[];
    uint4* XE4 = (uint4*)lds;             // [12][128] uint4 = 6144 floats
    uint4* WDC4= (uint4*)(lds + 6144);    // [32][128] uint4 = 16384 floats
    float* PP  = lds + 22528;             // 1024 (epilogue only)
    float* PPZ = lds + 23552;             // 1024
    float* PPA = lds + 24576;             // 1024 (APJ eighth-partials)
    float* APJP= lds + 25600;             // 160 (padded u=exp2(2L*APJ), stride-20 groups)
    float* DST = lds + 25760;             // 256: d, c
    float* CTX = lds + 26016;             // 128
    float* WSUM= lds + 26144;             // 16 wave softmax-sums
    float* YV  = lds + 26160;             // 96
    h2*    DCP = (h2*)(lds + 26256);      // 128 h2 (d pairs 0..63, c pairs 64..127)
    h2*    CXP = (h2*)(lds + 26384);      // 64 h2
    h2*    BEP = (h2*)(lds + 26448);      // 64 h2 (48 used)
    // total 26512 floats = 106048 B

    const int b = blockIdx.x, tid = threadIdx.x;
    const int u = tid & 511, hf = tid >> 9;    // z-half role
    const int j = tid & 127, og = tid >> 7;    // APJ-eighth role

    {   // x_enc -> LDS f16 t-pairs
        const float* xe_g = ws_xenc + b*TT*HH;
        for (int i = tid; i < 12*HH; i += 1024){
            int t8 = i >> 7, k = i & 127;
            uint4 qq;
            qq.x = pku(xe_g[(t8*8 + 0)*HH + k], xe_g[(t8*8 + 1)*HH + k]);
            qq.y = pku(xe_g[(t8*8 + 2)*HH + k], xe_g[(t8*8 + 3)*HH + k]);
            qq.z = pku(xe_g[(t8*8 + 4)*HH + k], xe_g[(t8*8 + 5)*HH + k]);
            qq.w = pku(xe_g[(t8*8 + 6)*HH + k], xe_g[(t8*8 + 7)*HH + k]);
            XE4[i] = qq;
        }
    }
    // ad_w1 rows 0..255 -> f16 LDS
    for (int i = tid; i < 4096; i += 1024){
        int jj = i & 127, i4g = i >> 7;
        int kbase = (i4g >> 2)*32 + (i4g & 3)*8;
        uint4 wv;
        wv.x = pku(ad_w1[(kbase+0)*HH + jj], ad_w1[(kbase+1)*HH + jj]);
        wv.y = pku(ad_w1[(kbase+2)*HH + jj], ad_w1[(kbase+3)*HH + jj]);
        wv.z = pku(ad_w1[(kbase+4)*HH + jj], ad_w1[(kbase+5)*HH + jj]);
        wv.w = pku(ad_w1[(kbase+6)*HH + jj], ad_w1[(kbase+7)*HH + jj]);
        WDC4[i] = wv;
    }
    if (tid < TT) YV[tid] = inputs[b*TT*FF + tid*FF + (FF-1)];
    if (tid < 128) DCP[tid] = pk(0.f, 0.f);
    if (tid < 256) DST[tid] = 0.f;

    // ---- step-invariant register caches ----
    h2 rp[32];                                  // dec_r half-column
    #pragma unroll
    for (int i = 0; i < 32; ++i)
        rp[i] = pk(dec_r[(hf*64 + 2*i)*G4 + u], dec_r[(hf*64 + 2*i+1)*G4 + u]);

    uint4 Greg[8];                              // G half-column (ctx weights)
    {
        const uint4* GQ = (const uint4*)Gp;
        #pragma unroll
        for (int g = 0; g < 8; ++g) Greg[g] = GQ[(hf*8 + g)*G4 + u];
    }

    // fused-softmax role: wave wv6 covers tp = wv6*6 + tpl (tpl<6), ogn intra-wave
    const int l6 = tid & 63, wv6 = tid >> 6;
    const int ogn = l6 & 7, tpl = l6 >> 3;
    const int tpn = wv6*6 + tpl;
    const bool act = (tpl < 6);
    // w2-folded factorization: w2*rcp(1+er*u) == rcp(iw + erw*u)
    float erw[16], iw[16], sumw2 = 0.f;
    {
        const float* xp_g = ws_xept + (b*HH + ogn*16)*TT + tpn;
        #pragma unroll
        for (int i = 0; i < 16; ++i){
            float w2v = ad_w2[ogn*16 + i];
            float ivv = 1.0f / w2v;
            iw[i] = ivv;
            sumw2 += w2v;
            float xp = act ? xp_g[i*TT] : 0.f;
            erw[i] = fexp2(2.0f*LOG2E * xp) * ivv;
        }
    }

    const float gbr = gb[u], gyr = gy[u];
    const float ab1 = (tid < 128) ? ad_b1[tid] : 0.f;
    __syncthreads();

    const uint4* DCP4 = (const uint4*)DCP;
    const uint4* CXP4 = (const uint4*)CXP;
    const uint4* BEP4 = (const uint4*)BEP;

    for (int t = 0; t < TT; ++t){
        float z = (hf == 0) ? (gbr + YV[t]*gyr) : 0.f;
        // P1: APJ eighth-partial (ALL threads)
        {
            float s0 = 0.f, s1 = 0.f;
            #pragma unroll
            for (int i = 0; i < 4; ++i){
                uint4 dq = DCP4[og*4 + i];              // wave-uniform broadcast
                uint4 wv = WDC4[(og*4 + i)*128 + j];    // lane-consecutive
                s0 = fdot2(u2h(dq.x), u2h(wv.x), s0);
                s1 = fdot2(u2h(dq.y), u2h(wv.y), s1);
                s0 = fdot2(u2h(dq.z), u2h(wv.z), s0);
                s1 = fdot2(u2h(dq.w), u2h(wv.w), s1);
            }
            PPA[og*128 + j] = s0 + s1;
        }
        // z-dot for waves 0-1 here (they reduce in the next window)
        if (tid < 128){
            float z2 = 0.f;
            #pragma unroll
            for (int i4 = 0; i4 < 8; ++i4){
                uint4 q = DCP4[hf*8 + i4];
                z  = fdot2(u2h(q.x), rp[i4*4+0], z);
                z2 = fdot2(u2h(q.y), rp[i4*4+1], z2);
                z  = fdot2(u2h(q.z), rp[i4*4+2], z);
                z2 = fdot2(u2h(q.w), rp[i4*4+3], z2);
            }
            z += z2;
        }
        __syncthreads();  // B1
        // P1b window: waves 0-1 reduce APJ (padded store); waves 2-15 z-dot
        if (tid < 128){
            float s = ab1;
            #pragma unroll
            for (int g = 0; g < 8; ++g) s += PPA[tid + 128*g];
            APJP[(tid >> 4)*20 + (tid & 15)] = fexp2(2.0f*LOG2E * s);
        } else {
            float z2 = 0.f;
            #pragma unroll
            for (int i4 = 0; i4 < 8; ++i4){
                uint4 q = DCP4[hf*8 + i4];
                z  = fdot2(u2h(q.x), rp[i4*4+0], z);
                z2 = fdot2(u2h(q.y), rp[i4*4+1], z2);
                z  = fdot2(u2h(q.z), rp[i4*4+2], z);
                z2 = fdot2(u2h(q.w), rp[i4*4+3], z2);
            }
            z += z2;
        }
        __syncthreads();  // B1b
        // P2' (fused P2+P3): e-partials + intra-wave og-reduce + exp +
        // BEP pack + per-wave softmax-sum. APJP reads now conflict-free.
        {
            float part = 0.f;
            if (act){
                float acc2 = 0.f;
                #pragma unroll
                for (int q4 = 0; q4 < 4; ++q4){
                    float4 uj = *(const float4*)&APJP[ogn*20 + q4*4];
                    acc2 += frcp(fmaf(erw[q4*4+0], uj.x, iw[q4*4+0]));
                    acc2 += frcp(fmaf(erw[q4*4+1], uj.y, iw[q4*4+1]));
                    acc2 += frcp(fmaf(erw[q4*4+2], uj.z, iw[q4*4+2]));
                    acc2 += frcp(fmaf(erw[q4*4+3], uj.w, iw[q4*4+3]));
                }
                part = sumw2 - 2.0f*acc2;
            }
            part += __shfl_xor(part, 1);
            part += __shfl_xor(part, 2);
            part += __shfl_xor(part, 4);
            float p = fexp2(part * LOG2E);
            float p2 = __shfl_xor(p, 8);
            if (act && ogn == 0 && !(tpl & 1))
                BEP[wv6*3 + (tpl >> 1)] = pk(p, p2);
            float pss = (act && ogn == 0) ? p : 0.f;
            pss += __shfl_xor(pss, 8);
            pss += __shfl_xor(pss, 16);
            pss += __shfl_xor(pss, 32);
            if (l6 == 0) WSUM[wv6] = pss;
        }
        __syncthreads();  // B2
        // P4: FULL ctx[k] (tid<128); ss from wave-sums, rs folded into scale
        if (tid < 128){
            float ssn = 0.f;
            #pragma unroll
            for (int g = 0; g < 16; ++g) ssn += WSUM[g];
            float rs = frcp(ssn);
            float s0 = 0.f, s1 = 0.f;
            #pragma unroll
            for (int t8 = 0; t8 < 12; t8 += 2){
                uint4 xq0 = XE4[t8*HH + tid],     bb0 = BEP4[t8];
                uint4 xq1 = XE4[(t8+1)*HH + tid], bb1 = BEP4[t8+1];
                s0 = fdot2(u2h(xq0.x), u2h(bb0.x), s0);
                s1 = fdot2(u2h(xq0.y), u2h(bb0.y), s1);
                s0 = fdot2(u2h(xq0.z), u2h(bb0.z), s0);
                s1 = fdot2(u2h(xq0.w), u2h(bb0.w), s1);
                s0 = fdot2(u2h(xq1.x), u2h(bb1.x), s0);
                s1 = fdot2(u2h(xq1.y), u2h(bb1.y), s1);
                s0 = fdot2(u2h(xq1.z), u2h(bb1.z), s0);
                s1 = fdot2(u2h(xq1.w), u2h(bb1.w), s1);
            }
            float cv = (s0 + s1) * rs;
            CTX[tid] = cv;
            float cv2 = __shfl_xor(cv, 1);
            if (!(tid & 1)) CXP[tid >> 1] = pk(cv, cv2);
        }
        __syncthreads();  // B4
        // P5: z-half += ctx @ G (G in registers, ctx broadcast from LDS)
        {
            float z2 = 0.f;
            #pragma unroll
            for (int gi = 0; gi < 8; ++gi){
                uint4 q  = Greg[gi];
                uint4 cc = CXP4[hf*8 + gi];
                z  = fdot2(u2h(q.x), u2h(cc.x), z);
                z2 = fdot2(u2h(q.y), u2h(cc.y), z2);
                z  = fdot2(u2h(q.z), u2h(cc.z), z);
                z2 = fdot2(u2h(q.w), u2h(cc.w), z2);
            }
            PPZ[hf*512 + u] = z + z2;
        }
        __syncthreads();  // B5
        // P6: gates (combine z-halves) + packed-state update
        if (tid < 128){
            int jj = tid;
            float zi = PPZ[jj]       + PPZ[512 + jj];
            float zf = PPZ[128 + jj] + PPZ[640 + jj];
            float zg = PPZ[256 + jj] + PPZ[768 + jj];
            float zo = PPZ[384 + jj] + PPZ[896 + jj];
            float iv = fsigmoid(zi);
            float fv = fsigmoid(zf);
            float gv = ftanh(zg);
            float ov = fsigmoid(zo);
            float cn = fv * DST[128 + jj] + iv * gv;
            float hn = ov * ftanh(cn);
            DST[128 + jj] = cn;
            DST[jj] = hn;
            float hn2 = __shfl_xor(hn, 1);
            float cn2 = __shfl_xor(cn, 1);
            if (!(jj & 1)){
                DCP[jj >> 1]        = pk(hn, hn2);
                DCP[64 + (jj >> 1)] = pk(cn, cn2);
            }
        }
        __syncthreads();  // B6
    }

    // output: y_pred = [d_n, ctx] @ ff_w + ff_b (fp32)
    {
        int jp = tid & 31, sg = tid >> 5;
        float a = 0.f;
        #pragma unroll
        for (int kk = 0; kk < 8; ++kk){
            int k = sg*8 + kk;
            float val = (k < 128) ? DST[k] : CTX[k - 128];
            a += val * ff_w[k*FF + jp];
        }
        PP[sg*32 + jp] = a;
    }
    __syncthreads();
    if (tid < 32){
        float o = ff_b[tid];
        #pragma unroll
        for (int s = 0; s < 32; ++s) o += PP[s*32 + tid];
        out[b*FF + tid] = o;
    }
}

// ---------------------------------------------------------------------------
extern "C" void kernel_launch(void* const* d_in, const int* in_sizes, int n_in,
                              void* d_out, int out_size, void* d_ws, size_t ws_size,
                              hipStream_t stream) {
    const float* inputs = (const float*)d_in[0];
    const float* enc_k  = (const float*)d_in[1];
    const float* enc_r  = (const float*)d_in[2];
    const float* enc_b  = (const float*)d_in[3];
    const float* ae_w1  = (const float*)d_in[4];
    const float* ae_b1  = (const float*)d_in[5];
    const float* ae_w2  = (const float*)d_in[6];
    // d_in[7] = ae_b2 (softmax-invariant, unused)
    const float* dec_k  = (const float*)d_in[8];
    const float* dec_r  = (const float*)d_in[9];
    const float* dec_b  = (const float*)d_in[10];
    const float* ad_w1  = (const float*)d_in[11];
    const float* ad_b1  = (const float*)d_in[12];
    const float* ad_w2  = (const float*)d_in[13];
    // d_in[14] = ad_b2 (softmax-invariant, unused)
    const float* fc_w   = (const float*)d_in[15];
    const float* fc_b   = (const float*)d_in[16];
    const float* ff_w   = (const float*)d_in[17];
    const float* ff_b   = (const float*)d_in[18];

    float* ws      = (float*)d_ws;
    float* ws_xenc = ws;                     // 64*96*128 floats
    float* ws_xept = ws + 786432;            // 64*128*96 floats
    h2*    Gp      = (h2*)(ws + 1572864);    // 32768 h2 (128 KB)
    float* gy      = ws + 1605632;           // 512
    float* gb      = ws + 1606144;           // 512

    hipFuncSetAttribute((const void*)k_enc, hipFuncAttributeMaxDynamicSharedMemorySize, 97568);
    hipFuncSetAttribute((const void*)k_dec, hipFuncAttributeMaxDynamicSharedMemorySize, 106048);

    // prep is merged into k_enc as blocks 64..81 (runs on idle CUs)
    k_enc<<<82, 1024, 97568, stream>>>(inputs, enc_k, enc_r, enc_b, ae_w1, ae_b1, ae_w2,
                                       ad_w1, fc_w, fc_b, dec_k, dec_b, Gp, gy, gb,
                                       ws_xenc, ws_xept);
    k_dec<<<64, 1024, 106048, stream>>>(inputs, dec_r, ad_w1, ad_b1, ad_w2, ff_w, ff_b,
                                        Gp, gy, gb, ws_xenc, ws_xept, (float*)d_out);
}